// Round 5
// baseline (92.471 us; speedup 1.0000x reference)
//
#include <hip/hip_runtime.h>
#include <hip/hip_fp16.h>

// Segment-mean of gathered embeddings, L2-resident gather version.
// Phase 0a: starts[s] via diff-scan of sorted segment_ids.
// Phase 0b: repack emb f32 [nitems][128] -> emb2 fp16 slice-major:
//           emb2[g][item][16] halves, g = dim-group (dims 16g..16g+15).
//           Per-group footprint = nitems*32 B = 3.2 MB -> fits 4 MB XCD L2.
//           TOTAL table = nitems*256 B = 25.6 MB (all 8 groups!).
// Phase 1:  gather+mean; block's dim-group g = blockIdx%8 (XCD-stable via
//           round-robin dispatch) so each XCD's L2 caches only its slice.

constexpr int D = 128;

typedef float  f32x2 __attribute__((ext_vector_type(2)));
typedef float  f32x4 __attribute__((ext_vector_type(4)));
typedef unsigned int u32x4 __attribute__((ext_vector_type(4)));

__global__ void find_starts_diff(const int* __restrict__ seg, int total,
                                 int nsess, int* __restrict__ starts) {
    int j = blockIdx.x * blockDim.x + threadIdx.x;
    if (j >= total) return;
    const int cur  = seg[j];
    const int prev = (j == 0) ? -1 : seg[j - 1];
    for (int s = prev + 1; s <= cur; ++s) starts[s] = j;   // covers starts[0]=0
    if (j == total - 1) {
        for (int s = cur + 1; s <= nsess; ++s) starts[s] = total;
    }
}

// One wave per item: 64 lanes read 512 B coalesced (float2/lane), convert to
// fp16, write each dim-group's 32 B chunk (8 lanes x 4 B, semi-coalesced).
__global__ __launch_bounds__(256)
void repack_kernel(const float* __restrict__ emb, __half* __restrict__ emb2,
                   int nitems) {
    const int item = blockIdx.x * 4 + (threadIdx.x >> 6);
    if (item >= nitems) return;
    const int lane = threadIdx.x & 63;             // covers dims 2*lane, 2*lane+1
    const f32x2 v = __builtin_nontemporal_load(
        reinterpret_cast<const f32x2*>(emb + (size_t)item * D) + lane);
    const __half2 h = __floats2half2_rn(v.x, v.y);
    const int g = lane >> 3;                       // dim-group 0..7
    const int o = lane & 7;                        // half2 slot within group
    __half2* dst = reinterpret_cast<__half2*>(
        emb2 + (size_t)g * nitems * 16 + (size_t)item * 16);
    dst[o] = h;
}

// One wave per (session, dim-group): 32 item-slots x 2 lanes (8 dims each).
// ids loaded coalesced once per 64 items and shfl-broadcast to slots.
__global__ __launch_bounds__(256)
void gather_mean_f16(const __half* __restrict__ emb2,
                     const int* __restrict__ ids,
                     const int* __restrict__ starts,
                     float* __restrict__ out,
                     int nitems, int nsess) {
    const int g    = blockIdx.x & 7;                           // XCD-stable slice
    const int sidx = (blockIdx.x >> 3) * 4 + (threadIdx.x >> 6);
    if (sidx >= nsess) return;
    const int lane = threadIdx.x & 63;
    const int slot = lane >> 1;        // item slot 0..31
    const int half = lane & 1;         // which 8-dim half of the 16-dim group

    const int beg = starts[sidx];
    const int end = starts[sidx + 1];
    const int len = end - beg;

    const __half* base = emb2 + (size_t)g * nitems * 16;

    float acc[8] = {0.f, 0.f, 0.f, 0.f, 0.f, 0.f, 0.f, 0.f};

    for (int c = 0; c < len; c += 64) {
        int idv = 0;
        if (c + lane < len)
            idv = __builtin_nontemporal_load(ids + beg + c + lane);
        #pragma unroll
        for (int t = 0; t < 2; ++t) {
            const int slotid = c + t * 32 + slot;
            const int id = __shfl(idv, t * 32 + slot);
            if (slotid < len) {
                const u32x4 raw = *reinterpret_cast<const u32x4*>(
                    base + (size_t)id * 16 + half * 8);
                const __half2* hp = reinterpret_cast<const __half2*>(&raw);
                #pragma unroll
                for (int k = 0; k < 4; ++k) {
                    const float2 f = __half22float2(hp[k]);
                    acc[2 * k]     += f.x;
                    acc[2 * k + 1] += f.y;
                }
            }
        }
    }

    // reduce across the 32 slots; parity (half bit0) preserved by offsets >= 2
    #pragma unroll
    for (int off = 2; off < 64; off <<= 1) {
        #pragma unroll
        for (int k = 0; k < 8; ++k)
            acc[k] += __shfl_xor(acc[k], off);
    }

    if (lane < 2) {
        const float inv = (len > 0) ? 1.0f / (float)len : 0.0f;
        float* dst = out + (size_t)sidx * D + g * 16 + half * 8;
        f32x4 o0 = {acc[0] * inv, acc[1] * inv, acc[2] * inv, acc[3] * inv};
        f32x4 o1 = {acc[4] * inv, acc[5] * inv, acc[6] * inv, acc[7] * inv};
        __builtin_nontemporal_store(o0, reinterpret_cast<f32x4*>(dst));
        __builtin_nontemporal_store(o1, reinterpret_cast<f32x4*>(dst) + 1);
    }
}

// ---------------- fallback (ws too small): round-2 direct f32 gather --------
__global__ __launch_bounds__(256)
void seg_mean_kernel(const float* __restrict__ emb,
                     const int* __restrict__ ids,
                     const int* __restrict__ starts,
                     float* __restrict__ out, int nsess) {
    const int tid  = threadIdx.x;
    const int s    = blockIdx.x * 4 + (tid >> 6);
    if (s >= nsess) return;
    const int lane = tid & 63;
    const int gq   = lane >> 5;
    const int l32  = lane & 31;

    const int beg = starts[s];
    const int end = starts[s + 1];

    float4 acc = make_float4(0.f, 0.f, 0.f, 0.f);
    for (int j = beg + gq; j < end; j += 2) {
        const int id = ids[j];
        const float4 v = reinterpret_cast<const float4*>(emb + (size_t)id * D)[l32];
        acc.x += v.x; acc.y += v.y; acc.z += v.z; acc.w += v.w;
    }
    acc.x += __shfl_down(acc.x, 32);
    acc.y += __shfl_down(acc.y, 32);
    acc.z += __shfl_down(acc.z, 32);
    acc.w += __shfl_down(acc.w, 32);
    if (lane < 32) {
        const int cnt = end - beg;
        const float inv = (cnt > 0) ? 1.0f / (float)cnt : 0.0f;
        const float4 o = make_float4(acc.x * inv, acc.y * inv,
                                     acc.z * inv, acc.w * inv);
        reinterpret_cast<float4*>(out + (size_t)s * D)[l32] = o;
    }
}

extern "C" void kernel_launch(void* const* d_in, const int* in_sizes, int n_in,
                              void* d_out, int out_size, void* d_ws, size_t ws_size,
                              hipStream_t stream) {
    const float* emb = (const float*)d_in[0];
    const int*   ids = (const int*)d_in[1];
    const int*   seg = (const int*)d_in[2];
    float*       out = (float*)d_out;

    const int total  = in_sizes[1];        // TOTAL_ITEMS
    const int nsess  = out_size / D;       // N_SESSIONS
    const int nitems = in_sizes[0] / D;    // N_ITEMS

    // FULL fp16 table: nitems * 128 dims * 2 B = 25.6 MB (8 groups x 3.2 MB)
    const size_t emb2_bytes = (size_t)nitems * D * 2;
    const size_t emb2_pad   = (emb2_bytes + 255) & ~(size_t)255;
    const size_t need       = emb2_pad + (size_t)(nsess + 1) * 4;

    if (ws_size >= need) {
        __half* emb2   = (__half*)d_ws;
        int*    starts = (int*)((char*)d_ws + emb2_pad);

        {
            const int threads = 256;
            const int blocks = (total + threads - 1) / threads;
            find_starts_diff<<<blocks, threads, 0, stream>>>(seg, total, nsess, starts);
        }
        {
            const int blocks = (nitems + 3) / 4;
            repack_kernel<<<blocks, 256, 0, stream>>>(emb, emb2, nitems);
        }
        {
            const int sblocks = (nsess + 3) / 4;
            gather_mean_f16<<<sblocks * 8, 256, 0, stream>>>(emb2, ids, starts,
                                                             out, nitems, nsess);
        }
    } else {
        int* starts = (int*)d_ws;
        {
            const int threads = 256;
            const int blocks = (total + threads - 1) / threads;
            find_starts_diff<<<blocks, threads, 0, stream>>>(seg, total, nsess, starts);
        }
        {
            const int blocks = (nsess + 3) / 4;
            seg_mean_kernel<<<blocks, 256, 0, stream>>>(emb, ids, starts, out, nsess);
        }
    }
}

// Round 7
// 78.106 us; speedup vs baseline: 1.1839x; 1.1839x over previous
//
#include <hip/hip_runtime.h>
#include <hip/hip_fp16.h>

// Segment-mean of gathered embeddings, L2-resident gather version.
// Phase 0a: starts[s] via diff-scan of sorted segment_ids.
// Phase 0b: repack emb f32 [nitems][128] -> emb2 fp16 slice-major:
//           emb2[g][item][16] halves, g = dim-group (dims 16g..16g+15).
//           Per-group footprint = nitems*32 B = 3.2 MB -> fits 4 MB XCD L2.
// Phase 1:  gather+mean, octet scheme: thread = (session, g, dim-pair dl).
//           g = blockIdx%8 rides round-robin block->XCD dispatch so each
//           XCD's L2 only holds its own 3.2 MB slice. No cross-lane ops.

constexpr int D = 128;

typedef float f32x2 __attribute__((ext_vector_type(2)));

__global__ void find_starts_diff(const int* __restrict__ seg, int total,
                                 int nsess, int* __restrict__ starts) {
    int j = blockIdx.x * blockDim.x + threadIdx.x;
    if (j >= total) return;
    const int cur  = seg[j];
    const int prev = (j == 0) ? -1 : seg[j - 1];
    for (int s = prev + 1; s <= cur; ++s) starts[s] = j;   // covers starts[0]=0
    if (j == total - 1) {
        for (int s = cur + 1; s <= nsess; ++s) starts[s] = total;
    }
}

// One wave per item: 64 lanes read 512 B coalesced (f32x2/lane), convert to
// fp16, write each dim-group's 32 B chunk (8 lanes x 4 B).
__global__ __launch_bounds__(256)
void repack_kernel(const float* __restrict__ emb, __half* __restrict__ emb2,
                   int nitems) {
    const int item = blockIdx.x * 4 + (threadIdx.x >> 6);
    if (item >= nitems) return;
    const int lane = threadIdx.x & 63;             // covers dims 2*lane, 2*lane+1
    const f32x2 v = __builtin_nontemporal_load(
        reinterpret_cast<const f32x2*>(emb + (size_t)item * D) + lane);
    const __half2 h = __floats2half2_rn(v.x, v.y);
    const int g = lane >> 3;                       // dim-group 0..7
    const int o = lane & 7;                        // half2 slot within group
    __half2* dst = reinterpret_cast<__half2*>(
        emb2 + (size_t)g * nitems * 16 + (size_t)item * 16);
    dst[o] = h;
}

// Thread = (session, dim-pair). Block = 32 sessions x 8 dim-pairs, all in
// dim-group g = blockIdx%8. Serial per-thread loop over the session's items,
// 4-way unrolled for MLP. Zero cross-lane operations.
__global__ __launch_bounds__(256)
void gather_mean_octet(const __half* __restrict__ emb2,
                       const int* __restrict__ ids,
                       const int* __restrict__ starts,
                       float* __restrict__ out,
                       int nitems, int nsess) {
    const int g    = blockIdx.x & 7;                          // XCD-stable slice
    const int sidx = (blockIdx.x >> 3) * 32 + (threadIdx.x >> 3);
    if (sidx >= nsess) return;
    const int dl   = threadIdx.x & 7;   // dims g*16 + 2*dl, +1

    const int beg = starts[sidx];
    const int len = starts[sidx + 1] - beg;

    const __half* p = emb2 + (size_t)g * nitems * 16 + dl * 2;
    const int* idp = ids + beg;

    float ax = 0.f, ay = 0.f;
    int j = 0;
    for (; j + 4 <= len; j += 4) {
        const int i0 = idp[j + 0];
        const int i1 = idp[j + 1];
        const int i2 = idp[j + 2];
        const int i3 = idp[j + 3];
        const __half2 h0 = *reinterpret_cast<const __half2*>(p + (size_t)i0 * 16);
        const __half2 h1 = *reinterpret_cast<const __half2*>(p + (size_t)i1 * 16);
        const __half2 h2 = *reinterpret_cast<const __half2*>(p + (size_t)i2 * 16);
        const __half2 h3 = *reinterpret_cast<const __half2*>(p + (size_t)i3 * 16);
        const float2 f0 = __half22float2(h0);
        const float2 f1 = __half22float2(h1);
        const float2 f2 = __half22float2(h2);
        const float2 f3 = __half22float2(h3);
        ax += f0.x + f1.x + f2.x + f3.x;
        ay += f0.y + f1.y + f2.y + f3.y;
    }
    for (; j < len; ++j) {
        const int id = idp[j];
        const float2 f = __half22float2(
            *reinterpret_cast<const __half2*>(p + (size_t)id * 16));
        ax += f.x; ay += f.y;
    }

    const float inv = (len > 0) ? 1.0f / (float)len : 0.0f;
    f32x2 o = {ax * inv, ay * inv};
    *reinterpret_cast<f32x2*>(out + (size_t)sidx * D + g * 16 + dl * 2) = o;
}

// ---------------- fallback (ws too small): round-2 direct f32 gather --------
__global__ __launch_bounds__(256)
void seg_mean_kernel(const float* __restrict__ emb,
                     const int* __restrict__ ids,
                     const int* __restrict__ starts,
                     float* __restrict__ out, int nsess) {
    const int tid  = threadIdx.x;
    const int s    = blockIdx.x * 4 + (tid >> 6);
    if (s >= nsess) return;
    const int lane = tid & 63;
    const int gq   = lane >> 5;
    const int l32  = lane & 31;

    const int beg = starts[s];
    const int end = starts[s + 1];

    float4 acc = make_float4(0.f, 0.f, 0.f, 0.f);
    for (int j = beg + gq; j < end; j += 2) {
        const int id = ids[j];
        const float4 v = reinterpret_cast<const float4*>(emb + (size_t)id * D)[l32];
        acc.x += v.x; acc.y += v.y; acc.z += v.z; acc.w += v.w;
    }
    acc.x += __shfl_down(acc.x, 32);
    acc.y += __shfl_down(acc.y, 32);
    acc.z += __shfl_down(acc.z, 32);
    acc.w += __shfl_down(acc.w, 32);
    if (lane < 32) {
        const int cnt = end - beg;
        const float inv = (cnt > 0) ? 1.0f / (float)cnt : 0.0f;
        const float4 o = make_float4(acc.x * inv, acc.y * inv,
                                     acc.z * inv, acc.w * inv);
        reinterpret_cast<float4*>(out + (size_t)s * D)[l32] = o;
    }
}

extern "C" void kernel_launch(void* const* d_in, const int* in_sizes, int n_in,
                              void* d_out, int out_size, void* d_ws, size_t ws_size,
                              hipStream_t stream) {
    const float* emb = (const float*)d_in[0];
    const int*   ids = (const int*)d_in[1];
    const int*   seg = (const int*)d_in[2];
    float*       out = (float*)d_out;

    const int total  = in_sizes[1];        // TOTAL_ITEMS
    const int nsess  = out_size / D;       // N_SESSIONS
    const int nitems = in_sizes[0] / D;    // N_ITEMS

    // FULL fp16 table: nitems * 128 dims * 2 B = 25.6 MB (8 groups x 3.2 MB)
    const size_t emb2_bytes = (size_t)nitems * D * 2;
    const size_t emb2_pad   = (emb2_bytes + 255) & ~(size_t)255;
    const size_t need       = emb2_pad + (size_t)(nsess + 1) * 4;

    if (ws_size >= need) {
        __half* emb2   = (__half*)d_ws;
        int*    starts = (int*)((char*)d_ws + emb2_pad);

        {
            const int threads = 256;
            const int blocks = (total + threads - 1) / threads;
            find_starts_diff<<<blocks, threads, 0, stream>>>(seg, total, nsess, starts);
        }
        {
            const int blocks = (nitems + 3) / 4;
            repack_kernel<<<blocks, 256, 0, stream>>>(emb, emb2, nitems);
        }
        {
            const int sgroups = (nsess + 31) / 32;
            gather_mean_octet<<<sgroups * 8, 256, 0, stream>>>(emb2, ids, starts,
                                                               out, nitems, nsess);
        }
    } else {
        int* starts = (int*)d_ws;
        {
            const int threads = 256;
            const int blocks = (total + threads - 1) / threads;
            find_starts_diff<<<blocks, threads, 0, stream>>>(seg, total, nsess, starts);
        }
        {
            const int blocks = (nsess + 3) / 4;
            seg_mean_kernel<<<blocks, 256, 0, stream>>>(emb, ids, starts, out, nsess);
        }
    }
}

// Round 8
// 63.351 us; speedup vs baseline: 1.4597x; 1.2329x over previous
//
#include <hip/hip_runtime.h>
#include <hip/hip_fp16.h>

// Segment-mean of gathered embeddings, L2-resident gather version.
// Phase 0a: starts[s] via diff-scan of sorted segment_ids.
// Phase 0b: repack emb f32 [nitems][128] -> emb2 fp16 slice-major:
//           emb2[g][item][16] halves, g = dim-group (dims 16g..16g+15).
//           Per-group footprint = nitems*32 B = 3.2 MB -> fits 4 MB XCD L2.
// Phase 1:  gather+mean, octet scheme: thread = (session, g, dim-pair dl),
//           g = blockIdx%8 rides round-robin block->XCD dispatch so each
//           XCD's L2 only holds its own slice. Block's ids staged in LDS
//           (32 consecutive sessions = one contiguous ids range).

constexpr int D = 128;
constexpr int IDS_CAP = 4096;     // 16 KB LDS; block mean ~1600 ids (+60 sigma)

typedef float f32x2 __attribute__((ext_vector_type(2)));

__global__ void find_starts_diff(const int* __restrict__ seg, int total,
                                 int nsess, int* __restrict__ starts) {
    int j = blockIdx.x * blockDim.x + threadIdx.x;
    if (j >= total) return;
    const int cur  = seg[j];
    const int prev = (j == 0) ? -1 : seg[j - 1];
    for (int s = prev + 1; s <= cur; ++s) starts[s] = j;   // covers starts[0]=0
    if (j == total - 1) {
        for (int s = cur + 1; s <= nsess; ++s) starts[s] = total;
    }
}

// One wave per item: 64 lanes read 512 B coalesced (f32x2/lane), convert to
// fp16, write each dim-group's 32 B chunk (8 lanes x 4 B).
__global__ __launch_bounds__(256)
void repack_kernel(const float* __restrict__ emb, __half* __restrict__ emb2,
                   int nitems) {
    const int item = blockIdx.x * 4 + (threadIdx.x >> 6);
    if (item >= nitems) return;
    const int lane = threadIdx.x & 63;             // covers dims 2*lane, 2*lane+1
    const f32x2 v = __builtin_nontemporal_load(
        reinterpret_cast<const f32x2*>(emb + (size_t)item * D) + lane);
    const __half2 h = __floats2half2_rn(v.x, v.y);
    const int g = lane >> 3;                       // dim-group 0..7
    const int o = lane & 7;                        // half2 slot within group
    __half2* dst = reinterpret_cast<__half2*>(
        emb2 + (size_t)g * nitems * 16 + (size_t)item * 16);
    dst[o] = h;
}

// Thread = (session, dim-pair). Block = 32 sessions x 8 dim-pairs, all in
// dim-group g = blockIdx%8. ids staged in LDS (contiguous range across the
// block's sessions); serial per-thread loop, 8-way unrolled. No cross-lane ops.
__global__ __launch_bounds__(256)
void gather_mean_octet(const __half* __restrict__ emb2,
                       const int* __restrict__ ids,
                       const int* __restrict__ starts,
                       float* __restrict__ out,
                       int nitems, int nsess) {
    __shared__ int lds_ids[IDS_CAP];

    const int g    = blockIdx.x & 7;                          // XCD-stable slice
    const int s0   = (blockIdx.x >> 3) * 32;
    const int sidx = s0 + (threadIdx.x >> 3);
    const int dl   = threadIdx.x & 7;   // dims g*16 + 2*dl, +1

    const int sEnd  = (s0 + 32 < nsess) ? s0 + 32 : nsess;
    const int base0 = starts[s0];
    const int range = starts[sEnd] - base0;
    const bool use_lds = (range <= IDS_CAP);

    if (use_lds) {
        for (int t = threadIdx.x; t < range; t += 256)
            lds_ids[t] = ids[base0 + t];
    }
    __syncthreads();

    if (sidx >= nsess) return;

    const int beg = starts[sidx];
    const int len = starts[sidx + 1] - beg;

    const __half* p = emb2 + (size_t)g * nitems * 16 + dl * 2;

    float ax = 0.f, ay = 0.f;

    if (use_lds) {
        const int* idp = lds_ids + (beg - base0);
        int j = 0;
        for (; j + 8 <= len; j += 8) {
            int id[8];
            #pragma unroll
            for (int k = 0; k < 8; ++k) id[k] = idp[j + k];
            float2 f[8];
            #pragma unroll
            for (int k = 0; k < 8; ++k)
                f[k] = __half22float2(
                    *reinterpret_cast<const __half2*>(p + (size_t)id[k] * 16));
            #pragma unroll
            for (int k = 0; k < 8; ++k) { ax += f[k].x; ay += f[k].y; }
        }
        for (; j < len; ++j) {
            const float2 f = __half22float2(
                *reinterpret_cast<const __half2*>(p + (size_t)idp[j] * 16));
            ax += f.x; ay += f.y;
        }
    } else {                                   // overflow fallback (rare)
        const int* idp = ids + beg;
        int j = 0;
        for (; j + 4 <= len; j += 4) {
            const int i0 = idp[j + 0];
            const int i1 = idp[j + 1];
            const int i2 = idp[j + 2];
            const int i3 = idp[j + 3];
            const float2 f0 = __half22float2(*reinterpret_cast<const __half2*>(p + (size_t)i0 * 16));
            const float2 f1 = __half22float2(*reinterpret_cast<const __half2*>(p + (size_t)i1 * 16));
            const float2 f2 = __half22float2(*reinterpret_cast<const __half2*>(p + (size_t)i2 * 16));
            const float2 f3 = __half22float2(*reinterpret_cast<const __half2*>(p + (size_t)i3 * 16));
            ax += f0.x + f1.x + f2.x + f3.x;
            ay += f0.y + f1.y + f2.y + f3.y;
        }
        for (; j < len; ++j) {
            const float2 f = __half22float2(
                *reinterpret_cast<const __half2*>(p + (size_t)idp[j] * 16));
            ax += f.x; ay += f.y;
        }
    }

    const float inv = (len > 0) ? 1.0f / (float)len : 0.0f;
    f32x2 o = {ax * inv, ay * inv};
    *reinterpret_cast<f32x2*>(out + (size_t)sidx * D + g * 16 + dl * 2) = o;
}

// ---------------- fallback (ws too small): round-2 direct f32 gather --------
__global__ __launch_bounds__(256)
void seg_mean_kernel(const float* __restrict__ emb,
                     const int* __restrict__ ids,
                     const int* __restrict__ starts,
                     float* __restrict__ out, int nsess) {
    const int tid  = threadIdx.x;
    const int s    = blockIdx.x * 4 + (tid >> 6);
    if (s >= nsess) return;
    const int lane = tid & 63;
    const int gq   = lane >> 5;
    const int l32  = lane & 31;

    const int beg = starts[s];
    const int end = starts[s + 1];

    float4 acc = make_float4(0.f, 0.f, 0.f, 0.f);
    for (int j = beg + gq; j < end; j += 2) {
        const int id = ids[j];
        const float4 v = reinterpret_cast<const float4*>(emb + (size_t)id * D)[l32];
        acc.x += v.x; acc.y += v.y; acc.z += v.z; acc.w += v.w;
    }
    acc.x += __shfl_down(acc.x, 32);
    acc.y += __shfl_down(acc.y, 32);
    acc.z += __shfl_down(acc.z, 32);
    acc.w += __shfl_down(acc.w, 32);
    if (lane < 32) {
        const int cnt = end - beg;
        const float inv = (cnt > 0) ? 1.0f / (float)cnt : 0.0f;
        const float4 o = make_float4(acc.x * inv, acc.y * inv,
                                     acc.z * inv, acc.w * inv);
        reinterpret_cast<float4*>(out + (size_t)s * D)[l32] = o;
    }
}

extern "C" void kernel_launch(void* const* d_in, const int* in_sizes, int n_in,
                              void* d_out, int out_size, void* d_ws, size_t ws_size,
                              hipStream_t stream) {
    const float* emb = (const float*)d_in[0];
    const int*   ids = (const int*)d_in[1];
    const int*   seg = (const int*)d_in[2];
    float*       out = (float*)d_out;

    const int total  = in_sizes[1];        // TOTAL_ITEMS
    const int nsess  = out_size / D;       // N_SESSIONS
    const int nitems = in_sizes[0] / D;    // N_ITEMS

    // FULL fp16 table: nitems * 128 dims * 2 B = 25.6 MB (8 groups x 3.2 MB)
    const size_t emb2_bytes = (size_t)nitems * D * 2;
    const size_t emb2_pad   = (emb2_bytes + 255) & ~(size_t)255;
    const size_t need       = emb2_pad + (size_t)(nsess + 1) * 4;

    if (ws_size >= need) {
        __half* emb2   = (__half*)d_ws;
        int*    starts = (int*)((char*)d_ws + emb2_pad);

        {
            const int threads = 256;
            const int blocks = (total + threads - 1) / threads;
            find_starts_diff<<<blocks, threads, 0, stream>>>(seg, total, nsess, starts);
        }
        {
            const int blocks = (nitems + 3) / 4;
            repack_kernel<<<blocks, 256, 0, stream>>>(emb, emb2, nitems);
        }
        {
            const int sgroups = (nsess + 31) / 32;
            gather_mean_octet<<<sgroups * 8, 256, 0, stream>>>(emb2, ids, starts,
                                                               out, nitems, nsess);
        }
    } else {
        int* starts = (int*)d_ws;
        {
            const int threads = 256;
            const int blocks = (total + threads - 1) / threads;
            find_starts_diff<<<blocks, threads, 0, stream>>>(seg, total, nsess, starts);
        }
        {
            const int blocks = (nsess + 3) / 4;
            seg_mean_kernel<<<blocks, 256, 0, stream>>>(emb, ids, starts, out, nsess);
        }
    }
}

// Round 9
// 55.314 us; speedup vs baseline: 1.6718x; 1.1453x over previous
//
#include <hip/hip_runtime.h>
#include <hip/hip_fp16.h>

// Segment-mean of gathered embeddings.
// Prep (one fused kernel): starts[] diff-scan + repack f32 -> fp16 in
//   4 slices of 32 dims: emb2[g][item][32] halves, g=0..3. Granule per
//   (item, slice) = 64 B (one L2 line). Slice = nitems*64 B = 6.4 MB.
// Gather: thread = (session, g, dl 0..15); g = blockIdx%4 -> XCD x always
//   sees g = x%4 (round-robin dispatch), so each XCD's L2 holds one slice
//   (oversubscribed 6.4/4 MB; misses are L3-served). Block = 16 sessions
//   x 16 dl; ids staged in LDS as prescaled byte offsets. No cross-lane ops.

constexpr int D = 128;
constexpr int IDS_CAP = 2048;     // 8 KB LDS; 16 sessions avg ~800 ids (44 sigma)

typedef float f32x2 __attribute__((ext_vector_type(2)));

// -------- fused prep: blocks [0, repack_blocks) repack, rest diff-scan -----
__global__ __launch_bounds__(256)
void prep_kernel(const float* __restrict__ emb, __half* __restrict__ emb2,
                 const int* __restrict__ seg, int* __restrict__ starts,
                 int nitems, int total, int nsess, int repack_blocks) {
    if ((int)blockIdx.x < repack_blocks) {
        // repack: one wave per item; lane covers dims 2*lane, 2*lane+1.
        const int item = blockIdx.x * 4 + (threadIdx.x >> 6);
        if (item >= nitems) return;
        const int lane = threadIdx.x & 63;
        const f32x2 v = __builtin_nontemporal_load(
            reinterpret_cast<const f32x2*>(emb + (size_t)item * D) + lane);
        const __half2 h = __floats2half2_rn(v.x, v.y);
        const int g = lane >> 4;                   // 32-dim slice 0..3
        const int o = lane & 15;                   // half2 slot within slice
        __half2* dst = reinterpret_cast<__half2*>(
            emb2 + (size_t)g * nitems * 32 + (size_t)item * 32);
        dst[o] = h;
    } else {
        const int j = ((int)blockIdx.x - repack_blocks) * 256 + threadIdx.x;
        if (j >= total) return;
        const int cur  = seg[j];
        const int prev = (j == 0) ? -1 : seg[j - 1];
        for (int s = prev + 1; s <= cur; ++s) starts[s] = j;
        if (j == total - 1) {
            for (int s = cur + 1; s <= nsess; ++s) starts[s] = total;
        }
    }
}

// Thread = (session, dim-pair dl). Block = 16 sessions x 16 dl, slice
// g = blockIdx%4. ids staged in LDS as byte offsets (id*64).
__global__ __launch_bounds__(256)
void gather_mean_hex(const __half* __restrict__ emb2,
                     const int* __restrict__ ids,
                     const int* __restrict__ starts,
                     float* __restrict__ out,
                     int nitems, int nsess) {
    __shared__ int lds_off[IDS_CAP];

    const int g    = blockIdx.x & 3;                          // XCD-stable slice
    const int s0   = (blockIdx.x >> 2) * 16;
    const int sidx = s0 + (threadIdx.x >> 4);
    const int dl   = threadIdx.x & 15;  // dims g*32 + 2*dl, +1

    const int sEnd  = (s0 + 16 < nsess) ? s0 + 16 : nsess;
    const int base0 = starts[s0];
    const int range = starts[sEnd] - base0;
    const bool use_lds = (range <= IDS_CAP);

    if (use_lds) {
        for (int t = threadIdx.x; t < range; t += 256)
            lds_off[t] = ids[base0 + t] << 6;     // prescaled byte offset
    }
    __syncthreads();

    if (sidx >= nsess) return;

    const int beg = starts[sidx];
    const int len = starts[sidx + 1] - beg;

    const char* pbase = reinterpret_cast<const char*>(emb2)
                      + (size_t)g * nitems * 64 + dl * 4;

    float ax = 0.f, ay = 0.f;

    if (use_lds) {
        const int* offp = lds_off + (beg - base0);
        int j = 0;
        for (; j + 8 <= len; j += 8) {
            int off[8];
            #pragma unroll
            for (int k = 0; k < 8; ++k) off[k] = offp[j + k];
            float2 f[8];
            #pragma unroll
            for (int k = 0; k < 8; ++k)
                f[k] = __half22float2(
                    *reinterpret_cast<const __half2*>(pbase + (size_t)off[k]));
            #pragma unroll
            for (int k = 0; k < 8; ++k) { ax += f[k].x; ay += f[k].y; }
        }
        for (; j < len; ++j) {
            const float2 f = __half22float2(
                *reinterpret_cast<const __half2*>(pbase + (size_t)offp[j]));
            ax += f.x; ay += f.y;
        }
    } else {                                   // overflow fallback (rare)
        const int* idp = ids + beg;
        for (int j = 0; j < len; ++j) {
            const float2 f = __half22float2(
                *reinterpret_cast<const __half2*>(pbase + ((size_t)idp[j] << 6)));
            ax += f.x; ay += f.y;
        }
    }

    const float inv = (len > 0) ? 1.0f / (float)len : 0.0f;
    f32x2 o = {ax * inv, ay * inv};
    *reinterpret_cast<f32x2*>(out + (size_t)sidx * D + g * 32 + dl * 2) = o;
}

// ---------------- fallback (ws too small): round-2 direct f32 gather --------
__global__ void find_starts_diff(const int* __restrict__ seg, int total,
                                 int nsess, int* __restrict__ starts) {
    int j = blockIdx.x * blockDim.x + threadIdx.x;
    if (j >= total) return;
    const int cur  = seg[j];
    const int prev = (j == 0) ? -1 : seg[j - 1];
    for (int s = prev + 1; s <= cur; ++s) starts[s] = j;
    if (j == total - 1) {
        for (int s = cur + 1; s <= nsess; ++s) starts[s] = total;
    }
}

__global__ __launch_bounds__(256)
void seg_mean_kernel(const float* __restrict__ emb,
                     const int* __restrict__ ids,
                     const int* __restrict__ starts,
                     float* __restrict__ out, int nsess) {
    const int tid  = threadIdx.x;
    const int s    = blockIdx.x * 4 + (tid >> 6);
    if (s >= nsess) return;
    const int lane = tid & 63;
    const int gq   = lane >> 5;
    const int l32  = lane & 31;

    const int beg = starts[s];
    const int end = starts[s + 1];

    float4 acc = make_float4(0.f, 0.f, 0.f, 0.f);
    for (int j = beg + gq; j < end; j += 2) {
        const int id = ids[j];
        const float4 v = reinterpret_cast<const float4*>(emb + (size_t)id * D)[l32];
        acc.x += v.x; acc.y += v.y; acc.z += v.z; acc.w += v.w;
    }
    acc.x += __shfl_down(acc.x, 32);
    acc.y += __shfl_down(acc.y, 32);
    acc.z += __shfl_down(acc.z, 32);
    acc.w += __shfl_down(acc.w, 32);
    if (lane < 32) {
        const int cnt = end - beg;
        const float inv = (cnt > 0) ? 1.0f / (float)cnt : 0.0f;
        const float4 o = make_float4(acc.x * inv, acc.y * inv,
                                     acc.z * inv, acc.w * inv);
        reinterpret_cast<float4*>(out + (size_t)s * D)[l32] = o;
    }
}

extern "C" void kernel_launch(void* const* d_in, const int* in_sizes, int n_in,
                              void* d_out, int out_size, void* d_ws, size_t ws_size,
                              hipStream_t stream) {
    const float* emb = (const float*)d_in[0];
    const int*   ids = (const int*)d_in[1];
    const int*   seg = (const int*)d_in[2];
    float*       out = (float*)d_out;

    const int total  = in_sizes[1];        // TOTAL_ITEMS
    const int nsess  = out_size / D;       // N_SESSIONS
    const int nitems = in_sizes[0] / D;    // N_ITEMS

    // FULL fp16 table: nitems * 128 dims * 2 B = 25.6 MB (4 slices x 6.4 MB)
    const size_t emb2_bytes = (size_t)nitems * D * 2;
    const size_t emb2_pad   = (emb2_bytes + 255) & ~(size_t)255;
    const size_t need       = emb2_pad + (size_t)(nsess + 1) * 4;

    if (ws_size >= need) {
        __half* emb2   = (__half*)d_ws;
        int*    starts = (int*)((char*)d_ws + emb2_pad);

        {
            const int repack_blocks = (nitems + 3) / 4;
            const int starts_blocks = (total + 255) / 256;
            prep_kernel<<<repack_blocks + starts_blocks, 256, 0, stream>>>(
                emb, emb2, seg, starts, nitems, total, nsess, repack_blocks);
        }
        {
            const int sgroups = (nsess + 15) / 16;
            gather_mean_hex<<<sgroups * 4, 256, 0, stream>>>(emb2, ids, starts,
                                                             out, nitems, nsess);
        }
    } else {
        int* starts = (int*)d_ws;
        {
            const int threads = 256;
            const int blocks = (total + threads - 1) / threads;
            find_starts_diff<<<blocks, threads, 0, stream>>>(seg, total, nsess, starts);
        }
        {
            const int blocks = (nsess + 3) / 4;
            seg_mean_kernel<<<blocks, 256, 0, stream>>>(emb, ids, starts, out, nsess);
        }
    }
}